// Round 6
// baseline (155.140 us; speedup 1.0000x reference)
//
#include <hip/hip_runtime.h>
#include <stdint.h>

// Problem constants
#define N_ROWS 32768
#define DIM    1024
#define HENC   512
#define NZ     64
#define KE     16
#define HEXP   256
#define NC     10

typedef __attribute__((ext_vector_type(8))) __bf16 bf16x8;
typedef __attribute__((ext_vector_type(4))) float f32x4;
typedef __attribute__((ext_vector_type(8))) unsigned short u16x8;
typedef __attribute__((ext_vector_type(4))) unsigned short u16x4;

__device__ __forceinline__ unsigned short f2bf(float f) {
    __bf16 h = (__bf16)f;  // RNE convert
    return __builtin_bit_cast(unsigned short, h);
}

// async global->LDS, 16B per lane. LDS dst must be wave-uniform (HW adds lane*16).
__device__ __forceinline__ void gload_lds16(void* lds, const void* gsrc) {
    __builtin_amdgcn_global_load_lds(
        (const __attribute__((address_space(1))) unsigned int*)gsrc,
        (__attribute__((address_space(3))) unsigned int*)lds,
        16, 0, 0);
}

// XOR swizzle in bf16-element space: flips 16B-granule bits 3..5 by row&7.
// Applied identically on write (or pre-swizzled global src) and read.
#define SWZ(col, row) ((col) ^ (((row) & 7) << 3))

// ---------------------------------------------------------------------------
// Kernel 0: cast+transpose all weights to bf16 so MFMA B-fragments are
// k-contiguous. enc_Wt [512][1024], z_Wt [64][512], W1t [16][256][64],
// W2t [16][16][256] (cols 10..15 zero-padded).
// ---------------------------------------------------------------------------
__global__ void prep_weights(const float* __restrict__ enc_W,
                             const float* __restrict__ z_W,
                             const float* __restrict__ W1,
                             const float* __restrict__ W2,
                             unsigned short* __restrict__ enc_Wt,
                             unsigned short* __restrict__ z_Wt,
                             unsigned short* __restrict__ W1t,
                             unsigned short* __restrict__ W2t) {
    int i = blockIdx.x * 256 + threadIdx.x;
    if (i < 524288) {                       // enc_Wt[n][k] = enc_W[k][n]
        int n = i >> 10, k = i & 1023;
        enc_Wt[i] = f2bf(enc_W[k * HENC + n]);
    } else if (i < 557056) {                // z_Wt[n][k] = z_W[k][n]
        int i2 = i - 524288;
        int n = i2 >> 9, k = i2 & 511;
        z_Wt[i2] = f2bf(z_W[k * NZ + n]);
    } else if (i < 819200) {                // W1t[e][h][d] = W1[e][d][h]
        int i3 = i - 557056;
        int e = i3 >> 14, rem = i3 & 16383;
        int h = rem >> 6, d = rem & 63;
        W1t[i3] = f2bf(W1[(e * NZ + d) * HEXP + h]);
    } else if (i < 884736) {                // W2t[e][c][h] = W2[e][h][c], pad c>=10
        int i4 = i - 819200;
        int e = i4 >> 12, rem = i4 & 4095;
        int c = rem >> 8, h = rem & 255;
        W2t[i4] = (c < NC) ? f2bf(W2[(e * HEXP + h) * NC + c]) : (unsigned short)0;
    }
}

// ---------------------------------------------------------------------------
// Kernel 1 (ROUND-6): hb = relu(X @ enc_W + enc_b) as bf16.
// 128x128 tile, BK=64, grid 1024 = 4 blocks/CU TOTAL, LDS 48 KB ->
// 3 RESIDENT blocks/CU (the round-0..5 data says resident-block overlap is
// the dominant lever for this latency-bound shape). Schedule keeps round-5's
// latency hiding: B double-buffered via async global_load_lds issued one
// step early (L2 latency under the 32-MFMA phase); A (X f32) register-
// prefetched at step top, cvt+ds_write after the MFMAs. 2 barriers/step.
// XOR-swizzled LDS both sides; __launch_bounds__(256,3) for 3 waves/EU.
// ---------------------------------------------------------------------------
__launch_bounds__(256, 3)
__global__ void gemm1(const float* __restrict__ X,
                      const unsigned short* __restrict__ Bt,   // enc_Wt [512][1024]
                      const float* __restrict__ enc_b,
                      unsigned short* __restrict__ hb) {
    __shared__ unsigned short As[128][64];        // 16 KB, single-buffered
    __shared__ unsigned short Bs[2][128][64];     // 32 KB, double-buffered
    const int t = threadIdx.x;
    const int lane = t & 63;
    const int w = t >> 6;
    const int g = lane >> 4;
    const int l15 = lane & 15;
    const int l7 = l15 & 7;
    const int wm = (w >> 1) * 64, wn = (w & 1) * 64;

    // bijective XCD swizzle: nwg=1024, 8 XCDs, n-tile fastest within a chunk
    const int bid = blockIdx.x;
    const int wgid = (bid & 7) * 128 + (bid >> 3);
    const int m0 = (wgid >> 2) * 128;
    const int n0 = (wgid & 3) * 128;

    // A staging lanes: thread covers rows (t>>4)+16*it, cols (t&15)*4
    const int arow = t >> 4, acolq = t & 15;
    const float* aptr = X + (size_t)(m0 + arow) * DIM + acolq * 4;
    const int ascol = SWZ(acolq * 4, arow);           // swizzled dest col (elems)
    // B gload_lds lanes: 1KB chunk = 8 rows x 64 cols bf16; source pre-swizzled
    const int brow0 = lane >> 3;
    const int bsrccol = SWZ((lane & 7) * 8, brow0);
    const unsigned short* bptr = Bt + (size_t)(n0 + brow0) * DIM + bsrccol;

    f32x4 acc[4][4];
#pragma unroll
    for (int i = 0; i < 4; ++i)
#pragma unroll
        for (int j = 0; j < 4; ++j) acc[i][j] = f32x4{0.f, 0.f, 0.f, 0.f};

    // prologue: stage step 0 (B into buf 0 async, A via regs)
    {
#pragma unroll
        for (int it = 0; it < 4; ++it) {
            const int chunk = it * 4 + w;           // 16 chunks of 8 rows
            gload_lds16(&Bs[0][chunk * 8][0], bptr + (size_t)chunk * 8 * DIM);
        }
        float4 a[8];
#pragma unroll
        for (int it = 0; it < 8; ++it)
            a[it] = *(const float4*)(aptr + (size_t)it * 16 * DIM);
#pragma unroll
        for (int it = 0; it < 8; ++it) {
            u16x4 p;
            p[0] = f2bf(a[it].x); p[1] = f2bf(a[it].y);
            p[2] = f2bf(a[it].z); p[3] = f2bf(a[it].w);
            *(u16x4*)&As[it * 16 + arow][ascol] = p;
        }
    }
    __syncthreads();

    float4 an[8];
    for (int step = 0; step < 16; ++step) {
        const int cur = step & 1, nxt = cur ^ 1;

        // issue next-step staging FIRST: B -> Bs[nxt] (async LDS), A -> regs
        if (step < 15) {
            const int k1 = (step + 1) * 64;
#pragma unroll
            for (int it = 0; it < 4; ++it) {
                const int chunk = it * 4 + w;
                gload_lds16(&Bs[nxt][chunk * 8][0],
                            bptr + (size_t)chunk * 8 * DIM + k1);
            }
#pragma unroll
            for (int it = 0; it < 8; ++it)
                an[it] = *(const float4*)(aptr + (size_t)it * 16 * DIM + k1);
        }

        // compute on current buffers: 2 kk halves x (4 row x 4 col) MFMA
#pragma unroll
        for (int kk = 0; kk < 2; ++kk) {
            const int ko = kk * 32 + g * 8;
            const int sko = SWZ(ko, l7);
            bf16x8 af[4], bfr[4];
#pragma unroll
            for (int i = 0; i < 4; ++i)
                af[i] = *(const bf16x8*)&As[wm + i * 16 + l15][sko];
#pragma unroll
            for (int j = 0; j < 4; ++j)
                bfr[j] = *(const bf16x8*)&Bs[cur][wn + j * 16 + l15][sko];
#pragma unroll
            for (int i = 0; i < 4; ++i)
#pragma unroll
                for (int j = 0; j < 4; ++j)
                    acc[i][j] = __builtin_amdgcn_mfma_f32_16x16x32_bf16(af[i], bfr[j], acc[i][j], 0, 0, 0);
        }
        __syncthreads();   // barrier1: As reads done; Bs[nxt] vmcnt drained

        // overwrite As with next step's A (X latency consumed by the MFMAs)
        if (step < 15) {
#pragma unroll
            for (int it = 0; it < 8; ++it) {
                u16x4 p;
                p[0] = f2bf(an[it].x); p[1] = f2bf(an[it].y);
                p[2] = f2bf(an[it].z); p[3] = f2bf(an[it].w);
                *(u16x4*)&As[it * 16 + arow][ascol] = p;
            }
        }
        __syncthreads();   // barrier2: As ready for next step
    }

    // epilogue: +bias, relu, bf16 store. C layout: col=lane&15, row=(lane>>4)*4+r
#pragma unroll
    for (int j = 0; j < 4; ++j) {
        int col = n0 + wn + j * 16 + l15;
        float bias = enc_b[col];
#pragma unroll
        for (int i = 0; i < 4; ++i) {
            int rbase = m0 + wm + i * 16 + g * 4;
#pragma unroll
            for (int r = 0; r < 4; ++r) {
                float v = acc[i][j][r] + bias;
                v = v > 0.f ? v : 0.f;
                hb[(size_t)(rbase + r) * HENC + col] = f2bf(v);
            }
        }
    }
}

// ---------------------------------------------------------------------------
// Kernel 2: z = hb @ z_W + z_b (f32 out). BM=64, 512 blocks (2/CU), 4 waves
// x 16 rows. A staged via global_load_lds (pre-swizzled src), double-buffered;
// B-frags straight from L2-resident zWt, hoisted to top of step. (unchanged)
// ---------------------------------------------------------------------------
__launch_bounds__(256, 2)
__global__ void gemm2(const unsigned short* __restrict__ hb,
                      const unsigned short* __restrict__ zWt,   // [64][512]
                      const float* __restrict__ z_b,
                      float* __restrict__ z) {
    __shared__ unsigned short As2[2][64][64];
    const int t = threadIdx.x, lane = t & 63, w = t >> 6;
    const int g = lane >> 4, l15 = lane & 15;
    const int l7 = l15 & 7;
    const int m0 = blockIdx.x * 64;
    const int brow0 = lane >> 3;
    const int bsrccol = SWZ((lane & 7) * 8, brow0);

    f32x4 acc[4];
#pragma unroll
    for (int j = 0; j < 4; ++j) acc[j] = f32x4{0.f, 0.f, 0.f, 0.f};

    // prologue: stage step 0 (64x64 bf16 = 8 chunks; 2 per wave)
#pragma unroll
    for (int it = 0; it < 2; ++it) {
        const int chunk = it * 4 + w;
        gload_lds16(&As2[0][chunk * 8][0],
                    hb + (size_t)(m0 + chunk * 8 + brow0) * HENC + bsrccol);
    }
    __syncthreads();

    for (int step = 0; step < 8; ++step) {
        const int cur = step & 1, nxt = cur ^ 1;
        // B frags for this step first (full step to cover L2 latency)
        bf16x8 bfr[2][4];
#pragma unroll
        for (int kk = 0; kk < 2; ++kk) {
            const int kg = step * 64 + kk * 32 + g * 8;
#pragma unroll
            for (int j = 0; j < 4; ++j)
                bfr[kk][j] = *(const bf16x8*)(zWt + (size_t)(j * 16 + l15) * HENC + kg);
        }
        if (step < 7) {
            const int k1 = (step + 1) * 64;
#pragma unroll
            for (int it = 0; it < 2; ++it) {
                const int chunk = it * 4 + w;
                gload_lds16(&As2[nxt][chunk * 8][0],
                            hb + (size_t)(m0 + chunk * 8 + brow0) * HENC + k1 + bsrccol);
            }
        }
#pragma unroll
        for (int kk = 0; kk < 2; ++kk) {
            const int ko = kk * 32 + g * 8;
            bf16x8 af = *(const bf16x8*)&As2[cur][w * 16 + l15][SWZ(ko, l7)];
#pragma unroll
            for (int j = 0; j < 4; ++j)
                acc[j] = __builtin_amdgcn_mfma_f32_16x16x32_bf16(af, bfr[kk][j], acc[j], 0, 0, 0);
        }
        __syncthreads();
    }
#pragma unroll
    for (int j = 0; j < 4; ++j) {
        int col = j * 16 + l15;
        float bias = z_b[col];
#pragma unroll
        for (int r = 0; r < 4; ++r) {
            int row = m0 + w * 16 + g * 4 + r;
            z[(size_t)row * NZ + col] = acc[j][r] + bias;
        }
    }
}

// ---------------------------------------------------------------------------
// Kernel 3: fused q + experts + combine. 512 blocks x 64 rows, 4 waves x 16
// rows. W1 staged in LDS double-buffered at half-expert granularity via async
// global_load_lds (next half issued at top of current half); W2/b1 frags
// direct from L2 hoisted to expert-top; eh per-wave (no barrier). (unchanged)
// ---------------------------------------------------------------------------
__launch_bounds__(256, 2)
__global__ void expert_kernel(const float* __restrict__ z,
                              const float* __restrict__ mu,
                              const unsigned short* __restrict__ W1t,  // [16][256][64]
                              const float* __restrict__ b1,
                              const unsigned short* __restrict__ W2t,  // [16][16][256]
                              const float* __restrict__ b2,
                              float* __restrict__ out) {
    __shared__ __align__(16) union SU {
        struct {
            float zs[64][68];    // padded: row stride 68 dwords == 4 mod 32
            float mus[16][68];
            float rn[64];
            float mun[16];
        } a;                                         // ~22.1 KB
        struct {
            unsigned short w1s[2][128][64];          // 32 KB double-buffered W1 halves
            unsigned short ehs[4][16][136];          // per-wave eh, 17.4 KB
        } b;
    } su;
    __shared__ float qs[64][16];                     // 4 KB

    const int t = threadIdx.x;
    const int lane = t & 63;
    const int w = t >> 6;
    const int g = lane >> 4;
    const int l15 = lane & 15;
    const int l7 = l15 & 7;
    const int r0 = blockIdx.x * 64;

    // P0: stage z block (64x64 f32) + mu into padded LDS
    {
#pragma unroll
        for (int it = 0; it < 4; ++it) {
            int idx = it * 256 + t;              // 1024 float4-slots
            int r = idx >> 4, c = (idx & 15) * 4;
            *(float4*)&su.a.zs[r][c] = *(const float4*)(z + (size_t)(r0 + r) * NZ + c);
        }
        int r = t >> 4, c = (t & 15) * 4;        // 256 float4-slots for mu
        *(float4*)&su.a.mus[r][c] = *(const float4*)(mu + (size_t)r * NZ + c);
    }
    __syncthreads();

    // P1a: row norms |z|^2 (t<64) and |mu|^2 (t in 64..79)
    if (t < 64) {
        float s = 0.f;
#pragma unroll
        for (int dq = 0; dq < 16; ++dq) {
            float4 v = *(const float4*)&su.a.zs[t][dq * 4];
            s += v.x * v.x + v.y * v.y + v.z * v.z + v.w * v.w;
        }
        su.a.rn[t] = s;
    } else if (t < 80) {
        int k = t - 64;
        float s = 0.f;
#pragma unroll
        for (int dq = 0; dq < 16; ++dq) {
            float4 v = *(const float4*)&su.a.mus[k][dq * 4];
            s += v.x * v.x + v.y * v.y + v.z * v.z + v.w * v.w;
        }
        su.a.mun[k] = s;
    }
    __syncthreads();

    // P1b: z fragments (kept for expert GEMMs) + dist via MFMA -> raw q
    bf16x8 az[2];
#pragma unroll
    for (int ks = 0; ks < 2; ++ks) {
        int row = w * 16 + l15;
        int ko = ks * 32 + g * 8;
        float4 lo = *(const float4*)&su.a.zs[row][ko];
        float4 hi = *(const float4*)&su.a.zs[row][ko + 4];
        u16x8 tmp;
        tmp[0] = f2bf(lo.x); tmp[1] = f2bf(lo.y); tmp[2] = f2bf(lo.z); tmp[3] = f2bf(lo.w);
        tmp[4] = f2bf(hi.x); tmp[5] = f2bf(hi.y); tmp[6] = f2bf(hi.z); tmp[7] = f2bf(hi.w);
        az[ks] = __builtin_bit_cast(bf16x8, tmp);
    }
    {
        bf16x8 bmu[2];
#pragma unroll
        for (int ks = 0; ks < 2; ++ks) {
            int ko = ks * 32 + g * 8;
            float4 lo = *(const float4*)&su.a.mus[l15][ko];
            float4 hi = *(const float4*)&su.a.mus[l15][ko + 4];
            u16x8 tmp;
            tmp[0] = f2bf(lo.x); tmp[1] = f2bf(lo.y); tmp[2] = f2bf(lo.z); tmp[3] = f2bf(lo.w);
            tmp[4] = f2bf(hi.x); tmp[5] = f2bf(hi.y); tmp[6] = f2bf(hi.z); tmp[7] = f2bf(hi.w);
            bmu[ks] = __builtin_bit_cast(bf16x8, tmp);
        }
        f32x4 dacc = f32x4{0.f, 0.f, 0.f, 0.f};
#pragma unroll
        for (int ks = 0; ks < 2; ++ks)
            dacc = __builtin_amdgcn_mfma_f32_16x16x32_bf16(az[ks], bmu[ks], dacc, 0, 0, 0);
#pragma unroll
        for (int r = 0; r < 4; ++r) {
            int rl = w * 16 + g * 4 + r;
            float dist = su.a.rn[rl] - 2.f * dacc[r] + su.a.mun[l15];
            qs[rl][l15] = 1.f / (1.f + dist);
        }
    }
    __syncthreads();

    // P1c: normalize q per row
    if (t < 64) {
        float s = 0.f;
#pragma unroll
        for (int k = 0; k < KE; ++k) s += qs[t][k];
        float inv = 1.f / s;
#pragma unroll
        for (int k = 0; k < KE; ++k) qs[t][k] *= inv;
    }
    __syncthreads();   // qs final, zs dead -> w1s/ehs may alias su.a

    // P3: expert loop with pipelined LDS weight staging.
    // W1 staging lanes: 1KB chunk = 8 rows x 64 cols bf16; source pre-swizzled.
    const int srow = lane >> 3;                       // 0..7 (row within chunk)
    const int scol = SWZ((lane & 7) * 8, srow);       // pre-swizzled source col

    // prologue: stage half 0 (expert 0, h0) into buf 0
#pragma unroll
    for (int it = 0; it < 4; ++it) {
        const int chunk = it * 4 + w;                 // 16 chunks of 8 rows
        gload_lds16(&su.b.w1s[0][chunk * 8][0],
                    W1t + (size_t)(chunk * 8 + srow) * NZ + scol);
    }
    __syncthreads();                                  // half0 staged

    float pacc[4] = {0.f, 0.f, 0.f, 0.f};
    unsigned short* eh = &su.b.ehs[w][0][0];          // per-wave [16][136]

    for (int e = 0; e < KE; ++e) {
        // expert-top: preload W2 frags + b1 (independent L2 loads, pipelined)
        const unsigned short* w2e = W2t + e * (16 * HEXP);
        bf16x8 w2f[8];
#pragma unroll
        for (int hh = 0; hh < 8; ++hh)
            w2f[hh] = *(const bf16x8*)(w2e + (size_t)l15 * HEXP + hh * 32 + g * 8);
        float b1v[2][8];
#pragma unroll
        for (int half = 0; half < 2; ++half)
#pragma unroll
            for (int j = 0; j < 8; ++j)
                b1v[half][j] = b1[e * HEXP + half * 128 + j * 16 + l15];

        f32x4 la = f32x4{0.f, 0.f, 0.f, 0.f};
#pragma unroll
        for (int half = 0; half < 2; ++half) {
            const int i = e * 2 + half;               // global half index 0..31
            const int cur = i & 1, nxt = cur ^ 1;

            // issue NEXT half's stage first (into buffer read 2 halves ago;
            // its vmcnt drains at this half's end-barrier, hidden under MFMAs)
            if (i + 1 < 2 * KE) {
                const int eg = (i + 1) >> 1;
                const int h1 = ((i + 1) & 1) * 128;
                const unsigned short* src =
                    W1t + (size_t)eg * (HEXP * NZ) + (size_t)(h1 + srow) * NZ + scol;
#pragma unroll
                for (int it = 0; it < 4; ++it) {
                    const int chunk = it * 4 + w;
                    gload_lds16(&su.b.w1s[nxt][chunk * 8][0],
                                src + (size_t)chunk * 8 * NZ);
                }
            }

            // eh = relu(z @ W1half + b1) : 16 rows x 128 h, from staged LDS
            f32x4 ea[8];
#pragma unroll
            for (int j = 0; j < 8; ++j) ea[j] = f32x4{0.f, 0.f, 0.f, 0.f};
#pragma unroll
            for (int ks = 0; ks < 2; ++ks) {
                const int sko = SWZ(ks * 32 + g * 8, l7);
#pragma unroll
                for (int j = 0; j < 8; ++j) {
                    bf16x8 bw = *(const bf16x8*)&su.b.w1s[cur][j * 16 + l15][sko];
                    ea[j] = __builtin_amdgcn_mfma_f32_16x16x32_bf16(az[ks], bw, ea[j], 0, 0, 0);
                }
            }
            // bias + relu + bf16 -> per-wave LDS (transpose round-trip)
#pragma unroll
            for (int j = 0; j < 8; ++j) {
#pragma unroll
                for (int r = 0; r < 4; ++r) {
                    float v = ea[j][r] + b1v[half][j];
                    v = v > 0.f ? v : 0.f;
                    eh[(g * 4 + r) * 136 + j * 16 + l15] = f2bf(v);
                }
            }
            // logits partial over this half's 128 h (wave-local read-back)
#pragma unroll
            for (int ks2 = 0; ks2 < 4; ++ks2) {
                bf16x8 ef = *(const bf16x8*)&eh[l15 * 136 + ks2 * 32 + g * 8];
                la = __builtin_amdgcn_mfma_f32_16x16x32_bf16(ef, w2f[half * 4 + ks2], la, 0, 0, 0);
            }
            __syncthreads();   // drains next-half stage; WAR-protects buffers
        }

        // combine: preds += q[:,e] * (logits + b2[e])
        float b2v = (l15 < NC) ? b2[e * NC + l15] : 0.f;
#pragma unroll
        for (int r = 0; r < 4; ++r) {
            int rl = w * 16 + g * 4 + r;
            pacc[r] += qs[rl][e] * (la[r] + b2v);
        }
    }

    // P4: store preds
    if (l15 < NC) {
#pragma unroll
        for (int r = 0; r < 4; ++r) {
            int row = r0 + w * 16 + g * 4 + r;
            out[(size_t)row * NC + l15] = pacc[r];
        }
    }
}

// ---------------------------------------------------------------------------
extern "C" void kernel_launch(void* const* d_in, const int* in_sizes, int n_in,
                              void* d_out, int out_size, void* d_ws, size_t ws_size,
                              hipStream_t stream) {
    const float* X     = (const float*)d_in[0];
    const float* enc_W = (const float*)d_in[1];
    const float* enc_b = (const float*)d_in[2];
    const float* z_W   = (const float*)d_in[3];
    const float* z_b   = (const float*)d_in[4];
    const float* mu    = (const float*)d_in[5];
    const float* W1    = (const float*)d_in[6];
    const float* b1    = (const float*)d_in[7];
    const float* W2    = (const float*)d_in[8];
    const float* b2    = (const float*)d_in[9];
    float* out = (float*)d_out;

    // workspace layout (total ~43.7 MB)
    char* ws = (char*)d_ws;
    unsigned short* hb     = (unsigned short*)(ws);              // 33,554,432 B
    float*          z      = (float*)(ws + 33554432);            //  8,388,608 B
    unsigned short* enc_Wt = (unsigned short*)(ws + 41943040);   //  1,048,576 B
    unsigned short* z_Wt   = (unsigned short*)(ws + 42991616);   //     65,536 B
    unsigned short* W1t    = (unsigned short*)(ws + 43057152);   //    524,288 B
    unsigned short* W2t    = (unsigned short*)(ws + 43581440);   //    131,072 B

    prep_weights<<<dim3(3456), dim3(256), 0, stream>>>(enc_W, z_W, W1, W2,
                                                       enc_Wt, z_Wt, W1t, W2t);
    gemm1<<<dim3(1024), dim3(256), 0, stream>>>(X, enc_Wt, enc_b, hb);
    gemm2<<<dim3(512), dim3(256), 0, stream>>>(hb, z_Wt, z_b, z);
    expert_kernel<<<dim3(512), dim3(256), 0, stream>>>(z, mu, W1t, b1, W2t, b2, out);
}

// Round 7
// 122.507 us; speedup vs baseline: 1.2664x; 1.2664x over previous
//
#include <hip/hip_runtime.h>
#include <stdint.h>

// Problem constants
#define N_ROWS 32768
#define DIM    1024
#define HENC   512
#define NZ     64
#define KE     16
#define HEXP   256
#define NC     10

typedef __attribute__((ext_vector_type(8))) __bf16 bf16x8;
typedef __attribute__((ext_vector_type(4))) float f32x4;
typedef __attribute__((ext_vector_type(8))) unsigned short u16x8;
typedef __attribute__((ext_vector_type(4))) unsigned short u16x4;

__device__ __forceinline__ unsigned short f2bf(float f) {
    __bf16 h = (__bf16)f;  // RNE convert
    return __builtin_bit_cast(unsigned short, h);
}

// async global->LDS, 16B per lane. LDS dst must be wave-uniform (HW adds lane*16).
__device__ __forceinline__ void gload_lds16(void* lds, const void* gsrc) {
    __builtin_amdgcn_global_load_lds(
        (const __attribute__((address_space(1))) unsigned int*)gsrc,
        (__attribute__((address_space(3))) unsigned int*)lds,
        16, 0, 0);
}

// XOR swizzle in bf16-element space: flips 16B-granule bits 3..5 by row&7.
// Applied identically on write (or pre-swizzled global src) and read.
#define SWZ(col, row) ((col) ^ (((row) & 7) << 3))

// ---------------------------------------------------------------------------
// Kernel 0: cast+transpose all weights to bf16 so MFMA B-fragments are
// k-contiguous. enc_Wt [512][1024], z_Wt [64][512], W1t [16][256][64],
// W2t [16][16][256] (cols 10..15 zero-padded).
// ---------------------------------------------------------------------------
__global__ void prep_weights(const float* __restrict__ enc_W,
                             const float* __restrict__ z_W,
                             const float* __restrict__ W1,
                             const float* __restrict__ W2,
                             unsigned short* __restrict__ enc_Wt,
                             unsigned short* __restrict__ z_Wt,
                             unsigned short* __restrict__ W1t,
                             unsigned short* __restrict__ W2t) {
    int i = blockIdx.x * 256 + threadIdx.x;
    if (i < 524288) {                       // enc_Wt[n][k] = enc_W[k][n]
        int n = i >> 10, k = i & 1023;
        enc_Wt[i] = f2bf(enc_W[k * HENC + n]);
    } else if (i < 557056) {                // z_Wt[n][k] = z_W[k][n]
        int i2 = i - 524288;
        int n = i2 >> 9, k = i2 & 511;
        z_Wt[i2] = f2bf(z_W[k * NZ + n]);
    } else if (i < 819200) {                // W1t[e][h][d] = W1[e][d][h]
        int i3 = i - 557056;
        int e = i3 >> 14, rem = i3 & 16383;
        int h = rem >> 6, d = rem & 63;
        W1t[i3] = f2bf(W1[(e * NZ + d) * HEXP + h]);
    } else if (i < 884736) {                // W2t[e][c][h] = W2[e][h][c], pad c>=10
        int i4 = i - 819200;
        int e = i4 >> 12, rem = i4 & 4095;
        int c = rem >> 8, h = rem & 255;
        W2t[i4] = (c < NC) ? f2bf(W2[(e * HEXP + h) * NC + c]) : (unsigned short)0;
    }
}

// ---------------------------------------------------------------------------
// Kernel 1 (ROUND-7): FUSED hb-GEMM + z-partial-GEMM.
// K-loop identical to round-5 best (BM=128 x BN=256, BK=64, 4 waves 2x2,
// wave tile 64x128, B dbuf via async global_load_lds issued a step early,
// A reg-prefetched, 80 KB LDS, grid 512 = 2 blocks/CU).
// NEW EPILOGUE: relu(acc+bias) -> swizzled bf16 LDS tile (64 KB, reuses the
// dead As/Bs space), barrier, then each wave computes the z-partial over
// this block's 256 hb-columns (zWt B-frags direct from L2) and stores a
// 128x64 f32 partial to zpart[n-half]. hb never touches HBM; gemm2 deleted.
// ---------------------------------------------------------------------------
__launch_bounds__(256, 2)
__global__ void gemm1(const float* __restrict__ X,
                      const unsigned short* __restrict__ Bt,   // enc_Wt [512][1024]
                      const float* __restrict__ enc_b,
                      const unsigned short* __restrict__ zWt,  // [64][512]
                      float* __restrict__ zpart) {             // [2][32768][64]
    __shared__ union G1U {
        struct {
            unsigned short As[128][64];       // 16 KB, single-buffered
            unsigned short Bs[2][256][64];    // 64 KB, double-buffered
        } s;
        unsigned short hbs[128][256];         // 64 KB epilogue hb tile
    } u;
    const int t = threadIdx.x;
    const int lane = t & 63;
    const int w = t >> 6;
    const int g = lane >> 4;
    const int l15 = lane & 15;
    const int l7 = l15 & 7;
    const int wm = (w >> 1) * 64;        // wave row base (0/64)
    const int wn = (w & 1) * 128;        // wave col base (0/128)

    // bijective XCD swizzle: nwg=512, 8 XCDs
    const int bid = blockIdx.x;
    const int wgid = (bid & 7) * 64 + (bid >> 3);
    const int m0 = (wgid >> 1) * 128;
    const int n0 = (wgid & 1) * 256;

    // A staging lanes: thread covers rows (t>>4)+16*it, cols (t&15)*4
    const int arow = t >> 4, acolq = t & 15;
    const float* aptr = X + (size_t)(m0 + arow) * DIM + acolq * 4;
    const int ascol = SWZ(acolq * 4, arow);           // swizzled dest col (elems)
    // B gload_lds lanes: 1KB chunk = 8 rows x 64 cols bf16; source pre-swizzled
    const int brow0 = lane >> 3;
    const int bsrccol = SWZ((lane & 7) * 8, brow0);
    const unsigned short* bptr = Bt + (size_t)(n0 + brow0) * DIM + bsrccol;

    f32x4 acc[4][8];
#pragma unroll
    for (int i = 0; i < 4; ++i)
#pragma unroll
        for (int j = 0; j < 8; ++j) acc[i][j] = f32x4{0.f, 0.f, 0.f, 0.f};

    // prologue: stage step 0 (B into buf 0, A into As)
    {
#pragma unroll
        for (int it = 0; it < 8; ++it) {
            const int chunk = it * 4 + w;           // 32 chunks of 8 rows
            gload_lds16(&u.s.Bs[0][chunk * 8][0], bptr + (size_t)chunk * 8 * DIM);
        }
        float4 a[8];
#pragma unroll
        for (int it = 0; it < 8; ++it)
            a[it] = *(const float4*)(aptr + (size_t)it * 16 * DIM);
#pragma unroll
        for (int it = 0; it < 8; ++it) {
            u16x4 p;
            p[0] = f2bf(a[it].x); p[1] = f2bf(a[it].y);
            p[2] = f2bf(a[it].z); p[3] = f2bf(a[it].w);
            *(u16x4*)&u.s.As[it * 16 + arow][ascol] = p;
        }
    }
    __syncthreads();

    float4 an[8];
    for (int step = 0; step < 16; ++step) {
        const int cur = step & 1, nxt = cur ^ 1;

        // issue next-step staging FIRST: B -> Bs[nxt] (async LDS), A -> regs
        if (step < 15) {
            const int k1 = (step + 1) * 64;
#pragma unroll
            for (int it = 0; it < 8; ++it) {
                const int chunk = it * 4 + w;
                gload_lds16(&u.s.Bs[nxt][chunk * 8][0],
                            bptr + (size_t)chunk * 8 * DIM + k1);
            }
#pragma unroll
            for (int it = 0; it < 8; ++it)
                an[it] = *(const float4*)(aptr + (size_t)it * 16 * DIM + k1);
        }

        // compute on current buffers: 2 kk halves x (4 row x 8 col) MFMA
#pragma unroll
        for (int kk = 0; kk < 2; ++kk) {
            const int ko = kk * 32 + g * 8;
            const int sko = SWZ(ko, l7);
            bf16x8 af[4], bfr[8];
#pragma unroll
            for (int i = 0; i < 4; ++i)
                af[i] = *(const bf16x8*)&u.s.As[wm + i * 16 + l15][sko];
#pragma unroll
            for (int j = 0; j < 8; ++j)
                bfr[j] = *(const bf16x8*)&u.s.Bs[cur][wn + j * 16 + l15][sko];
#pragma unroll
            for (int i = 0; i < 4; ++i)
#pragma unroll
                for (int j = 0; j < 8; ++j)
                    acc[i][j] = __builtin_amdgcn_mfma_f32_16x16x32_bf16(af[i], bfr[j], acc[i][j], 0, 0, 0);
        }
        __syncthreads();   // barrier1: As reads done; Bs[nxt] vmcnt drained

        // overwrite As with next step's A (X latency consumed by the MFMAs)
        if (step < 15) {
#pragma unroll
            for (int it = 0; it < 8; ++it) {
                u16x4 p;
                p[0] = f2bf(an[it].x); p[1] = f2bf(an[it].y);
                p[2] = f2bf(an[it].z); p[3] = f2bf(an[it].w);
                *(u16x4*)&u.s.As[it * 16 + arow][ascol] = p;
            }
        }
        __syncthreads();   // barrier2: As ready for next step
    }

    // ---- fused epilogue part 1: relu(acc+bias) -> swizzled bf16 LDS tile ----
    // (As/Bs dead after the final barrier; hbs aliases them)
#pragma unroll
    for (int j = 0; j < 8; ++j) {
        const int col = wn + j * 16 + l15;            // local col 0..255
        const float bias = enc_b[n0 + col];
#pragma unroll
        for (int i = 0; i < 4; ++i) {
            const int rb = wm + i * 16 + g * 4;
#pragma unroll
            for (int r = 0; r < 4; ++r) {
                float v = acc[i][j][r] + bias;
                v = v > 0.f ? v : 0.f;
                u.hbs[rb + r][SWZ(col, rb + r)] = f2bf(v);
            }
        }
    }
    __syncthreads();

    // ---- fused epilogue part 2: z-partial = hbs @ zWt[:, n0:n0+256] ----
    // wave w: rows w*32..w*32+31 (local), all 64 z-cols, K=256.
    {
        f32x4 zacc[2][4];
#pragma unroll
        for (int i2 = 0; i2 < 2; ++i2)
#pragma unroll
            for (int j2 = 0; j2 < 4; ++j2) zacc[i2][j2] = f32x4{0.f, 0.f, 0.f, 0.f};

        const unsigned short* zwB = zWt + n0;         // k-offset into [64][512]
#pragma unroll
        for (int ks = 0; ks < 8; ++ks) {
            const int k = ks * 32 + g * 8;            // local k 0..255
            bf16x8 bz[4];
#pragma unroll
            for (int j2 = 0; j2 < 4; ++j2)
                bz[j2] = *(const bf16x8*)(zwB + (size_t)(j2 * 16 + l15) * HENC + k);
#pragma unroll
            for (int i2 = 0; i2 < 2; ++i2) {
                const int row = w * 32 + i2 * 16 + l15;
                bf16x8 af = *(const bf16x8*)&u.hbs[row][SWZ(k, row)];
#pragma unroll
                for (int j2 = 0; j2 < 4; ++j2)
                    zacc[i2][j2] = __builtin_amdgcn_mfma_f32_16x16x32_bf16(af, bz[j2], zacc[i2][j2], 0, 0, 0);
            }
        }
        // store partial (f32). C layout: col=l15, row=g*4+r
        float* zp = zpart + (size_t)(n0 ? 1 : 0) * N_ROWS * NZ;
#pragma unroll
        for (int i2 = 0; i2 < 2; ++i2)
#pragma unroll
            for (int j2 = 0; j2 < 4; ++j2) {
                const int colz = j2 * 16 + l15;
#pragma unroll
                for (int r = 0; r < 4; ++r) {
                    const int rowz = m0 + w * 32 + i2 * 16 + g * 4 + r;
                    zp[(size_t)rowz * NZ + colz] = zacc[i2][j2][r];
                }
            }
    }
}

// ---------------------------------------------------------------------------
// Kernel 3: fused q + experts + combine. 512 blocks x 64 rows, 4 waves x 16
// rows. P0 now sums the two z-partials + z_b. W1 staged in LDS double-
// buffered at half-expert granularity via async global_load_lds; W2/b1 frags
// direct from L2 hoisted to expert-top; eh per-wave (no barrier).
// ---------------------------------------------------------------------------
__launch_bounds__(256, 2)
__global__ void expert_kernel(const float* __restrict__ zpart,  // [2][32768][64]
                              const float* __restrict__ z_b,
                              const float* __restrict__ mu,
                              const unsigned short* __restrict__ W1t,  // [16][256][64]
                              const float* __restrict__ b1,
                              const unsigned short* __restrict__ W2t,  // [16][16][256]
                              const float* __restrict__ b2,
                              float* __restrict__ out) {
    __shared__ __align__(16) union SU {
        struct {
            float zs[64][68];    // padded: row stride 68 dwords == 4 mod 32
            float mus[16][68];
            float rn[64];
            float mun[16];
        } a;                                         // ~22.1 KB
        struct {
            unsigned short w1s[2][128][64];          // 32 KB double-buffered W1 halves
            unsigned short ehs[4][16][136];          // per-wave eh, 17.4 KB
        } b;
    } su;
    __shared__ float qs[64][16];                     // 4 KB

    const int t = threadIdx.x;
    const int lane = t & 63;
    const int w = t >> 6;
    const int g = lane >> 4;
    const int l15 = lane & 15;
    const int l7 = l15 & 7;
    const int r0 = blockIdx.x * 64;

    // P0: z = zpart0 + zpart1 + z_b (64x64 f32) + mu into padded LDS
    {
        const float* zp0 = zpart;
        const float* zp1 = zpart + (size_t)N_ROWS * NZ;
#pragma unroll
        for (int it = 0; it < 4; ++it) {
            int idx = it * 256 + t;              // 1024 float4-slots
            int r = idx >> 4, c = (idx & 15) * 4;
            float4 a = *(const float4*)(zp0 + (size_t)(r0 + r) * NZ + c);
            float4 b = *(const float4*)(zp1 + (size_t)(r0 + r) * NZ + c);
            float4 zb = *(const float4*)(z_b + c);
            float4 s;
            s.x = a.x + b.x + zb.x; s.y = a.y + b.y + zb.y;
            s.z = a.z + b.z + zb.z; s.w = a.w + b.w + zb.w;
            *(float4*)&su.a.zs[r][c] = s;
        }
        int r = t >> 4, c = (t & 15) * 4;        // 256 float4-slots for mu
        *(float4*)&su.a.mus[r][c] = *(const float4*)(mu + (size_t)r * NZ + c);
    }
    __syncthreads();

    // P1a: row norms |z|^2 (t<64) and |mu|^2 (t in 64..79)
    if (t < 64) {
        float s = 0.f;
#pragma unroll
        for (int dq = 0; dq < 16; ++dq) {
            float4 v = *(const float4*)&su.a.zs[t][dq * 4];
            s += v.x * v.x + v.y * v.y + v.z * v.z + v.w * v.w;
        }
        su.a.rn[t] = s;
    } else if (t < 80) {
        int k = t - 64;
        float s = 0.f;
#pragma unroll
        for (int dq = 0; dq < 16; ++dq) {
            float4 v = *(const float4*)&su.a.mus[k][dq * 4];
            s += v.x * v.x + v.y * v.y + v.z * v.z + v.w * v.w;
        }
        su.a.mun[k] = s;
    }
    __syncthreads();

    // P1b: z fragments (kept for expert GEMMs) + dist via MFMA -> raw q
    bf16x8 az[2];
#pragma unroll
    for (int ks = 0; ks < 2; ++ks) {
        int row = w * 16 + l15;
        int ko = ks * 32 + g * 8;
        float4 lo = *(const float4*)&su.a.zs[row][ko];
        float4 hi = *(const float4*)&su.a.zs[row][ko + 4];
        u16x8 tmp;
        tmp[0] = f2bf(lo.x); tmp[1] = f2bf(lo.y); tmp[2] = f2bf(lo.z); tmp[3] = f2bf(lo.w);
        tmp[4] = f2bf(hi.x); tmp[5] = f2bf(hi.y); tmp[6] = f2bf(hi.z); tmp[7] = f2bf(hi.w);
        az[ks] = __builtin_bit_cast(bf16x8, tmp);
    }
    {
        bf16x8 bmu[2];
#pragma unroll
        for (int ks = 0; ks < 2; ++ks) {
            int ko = ks * 32 + g * 8;
            float4 lo = *(const float4*)&su.a.mus[l15][ko];
            float4 hi = *(const float4*)&su.a.mus[l15][ko + 4];
            u16x8 tmp;
            tmp[0] = f2bf(lo.x); tmp[1] = f2bf(lo.y); tmp[2] = f2bf(lo.z); tmp[3] = f2bf(lo.w);
            tmp[4] = f2bf(hi.x); tmp[5] = f2bf(hi.y); tmp[6] = f2bf(hi.z); tmp[7] = f2bf(hi.w);
            bmu[ks] = __builtin_bit_cast(bf16x8, tmp);
        }
        f32x4 dacc = f32x4{0.f, 0.f, 0.f, 0.f};
#pragma unroll
        for (int ks = 0; ks < 2; ++ks)
            dacc = __builtin_amdgcn_mfma_f32_16x16x32_bf16(az[ks], bmu[ks], dacc, 0, 0, 0);
#pragma unroll
        for (int r = 0; r < 4; ++r) {
            int rl = w * 16 + g * 4 + r;
            float dist = su.a.rn[rl] - 2.f * dacc[r] + su.a.mun[l15];
            qs[rl][l15] = 1.f / (1.f + dist);
        }
    }
    __syncthreads();

    // P1c: normalize q per row
    if (t < 64) {
        float s = 0.f;
#pragma unroll
        for (int k = 0; k < KE; ++k) s += qs[t][k];
        float inv = 1.f / s;
#pragma unroll
        for (int k = 0; k < KE; ++k) qs[t][k] *= inv;
    }
    __syncthreads();   // qs final, zs dead -> w1s/ehs may alias su.a

    // P3: expert loop with pipelined LDS weight staging.
    // W1 staging lanes: 1KB chunk = 8 rows x 64 cols bf16; source pre-swizzled.
    const int srow = lane >> 3;                       // 0..7 (row within chunk)
    const int scol = SWZ((lane & 7) * 8, srow);       // pre-swizzled source col

    // prologue: stage half 0 (expert 0, h0) into buf 0
#pragma unroll
    for (int it = 0; it < 4; ++it) {
        const int chunk = it * 4 + w;                 // 16 chunks of 8 rows
        gload_lds16(&su.b.w1s[0][chunk * 8][0],
                    W1t + (size_t)(chunk * 8 + srow) * NZ + scol);
    }
    __syncthreads();                                  // half0 staged

    float pacc[4] = {0.f, 0.f, 0.f, 0.f};
    unsigned short* eh = &su.b.ehs[w][0][0];          // per-wave [16][136]

    for (int e = 0; e < KE; ++e) {
        // expert-top: preload W2 frags + b1 (independent L2 loads, pipelined)
        const unsigned short* w2e = W2t + e * (16 * HEXP);
        bf16x8 w2f[8];
#pragma unroll
        for (int hh = 0; hh < 8; ++hh)
            w2f[hh] = *(const bf16x8*)(w2e + (size_t)l15 * HEXP + hh * 32 + g * 8);
        float b1v[2][8];
#pragma unroll
        for (int half = 0; half < 2; ++half)
#pragma unroll
            for (int j = 0; j < 8; ++j)
                b1v[half][j] = b1[e * HEXP + half * 128 + j * 16 + l15];

        f32x4 la = f32x4{0.f, 0.f, 0.f, 0.f};
#pragma unroll
        for (int half = 0; half < 2; ++half) {
            const int i = e * 2 + half;               // global half index 0..31
            const int cur = i & 1, nxt = cur ^ 1;

            // issue NEXT half's stage first (into buffer read 2 halves ago;
            // its vmcnt drains at this half's end-barrier, hidden under MFMAs)
            if (i + 1 < 2 * KE) {
                const int eg = (i + 1) >> 1;
                const int h1 = ((i + 1) & 1) * 128;
                const unsigned short* src =
                    W1t + (size_t)eg * (HEXP * NZ) + (size_t)(h1 + srow) * NZ + scol;
#pragma unroll
                for (int it = 0; it < 4; ++it) {
                    const int chunk = it * 4 + w;
                    gload_lds16(&su.b.w1s[nxt][chunk * 8][0],
                                src + (size_t)chunk * 8 * NZ);
                }
            }

            // eh = relu(z @ W1half + b1) : 16 rows x 128 h, from staged LDS
            f32x4 ea[8];
#pragma unroll
            for (int j = 0; j < 8; ++j) ea[j] = f32x4{0.f, 0.f, 0.f, 0.f};
#pragma unroll
            for (int ks = 0; ks < 2; ++ks) {
                const int sko = SWZ(ks * 32 + g * 8, l7);
#pragma unroll
                for (int j = 0; j < 8; ++j) {
                    bf16x8 bw = *(const bf16x8*)&su.b.w1s[cur][j * 16 + l15][sko];
                    ea[j] = __builtin_amdgcn_mfma_f32_16x16x32_bf16(az[ks], bw, ea[j], 0, 0, 0);
                }
            }
            // bias + relu + bf16 -> per-wave LDS (transpose round-trip)
#pragma unroll
            for (int j = 0; j < 8; ++j) {
#pragma unroll
                for (int r = 0; r < 4; ++r) {
                    float v = ea[j][r] + b1v[half][j];
                    v = v > 0.f ? v : 0.f;
                    eh[(g * 4 + r) * 136 + j * 16 + l15] = f2bf(v);
                }
            }
            // logits partial over this half's 128 h (wave-local read-back)
#pragma unroll
            for (int ks2 = 0; ks2 < 4; ++ks2) {
                bf16x8 ef = *(const bf16x8*)&eh[l15 * 136 + ks2 * 32 + g * 8];
                la = __builtin_amdgcn_mfma_f32_16x16x32_bf16(ef, w2f[half * 4 + ks2], la, 0, 0, 0);
            }
            __syncthreads();   // drains next-half stage; WAR-protects buffers
        }

        // combine: preds += q[:,e] * (logits + b2[e])
        float b2v = (l15 < NC) ? b2[e * NC + l15] : 0.f;
#pragma unroll
        for (int r = 0; r < 4; ++r) {
            int rl = w * 16 + g * 4 + r;
            pacc[r] += qs[rl][e] * (la[r] + b2v);
        }
    }

    // P4: store preds
    if (l15 < NC) {
#pragma unroll
        for (int r = 0; r < 4; ++r) {
            int row = r0 + w * 16 + g * 4 + r;
            out[(size_t)row * NC + l15] = pacc[r];
        }
    }
}

// ---------------------------------------------------------------------------
extern "C" void kernel_launch(void* const* d_in, const int* in_sizes, int n_in,
                              void* d_out, int out_size, void* d_ws, size_t ws_size,
                              hipStream_t stream) {
    const float* X     = (const float*)d_in[0];
    const float* enc_W = (const float*)d_in[1];
    const float* enc_b = (const float*)d_in[2];
    const float* z_W   = (const float*)d_in[3];
    const float* z_b   = (const float*)d_in[4];
    const float* mu    = (const float*)d_in[5];
    const float* W1    = (const float*)d_in[6];
    const float* b1    = (const float*)d_in[7];
    const float* W2    = (const float*)d_in[8];
    const float* b2    = (const float*)d_in[9];
    float* out = (float*)d_out;

    // workspace layout (~18.5 MB)
    char* ws = (char*)d_ws;
    float*          zpart  = (float*)(ws);                       // 16,777,216 B
    unsigned short* enc_Wt = (unsigned short*)(ws + 16777216);   //  1,048,576 B
    unsigned short* z_Wt   = (unsigned short*)(ws + 17825792);   //     65,536 B
    unsigned short* W1t    = (unsigned short*)(ws + 17891328);   //    524,288 B
    unsigned short* W2t    = (unsigned short*)(ws + 18415616);   //    131,072 B

    prep_weights<<<dim3(3456), dim3(256), 0, stream>>>(enc_W, z_W, W1, W2,
                                                       enc_Wt, z_Wt, W1t, W2t);
    gemm1<<<dim3(512), dim3(256), 0, stream>>>(X, enc_Wt, enc_b, z_Wt, zpart);
    expert_kernel<<<dim3(512), dim3(256), 0, stream>>>(zpart, z_b, mu, W1t, b1, W2t, b2, out);
}